// Round 1
// baseline (223.402 us; speedup 1.0000x reference)
//
#include <hip/hip_runtime.h>
#include <hip/hip_bf16.h>

// Element-wise threshold-round kernel with reversed output order.
// y[i] = (frac(x[i]) > thr) ? rint(x[i]) : floor(x[i]);  out = y[::-1]
//
// Memory-bound: 2^25 fp32 in + 2^25 fp32 out = 256 MiB HBM traffic.
// float4 vectorization both directions; reversed store done as a
// component-swapped float4 at mirrored offset so stores stay 16B-aligned
// and contiguous per wave.

__global__ __launch_bounds__(256) void threshold_rev_kernel(
    const float* __restrict__ x,
    const float* __restrict__ threshold,
    float* __restrict__ out,
    int n4 /* number of float4 groups = N/4 */,
    int n  /* total elements */) {
    const float thr = threshold[0];
    int t = blockIdx.x * blockDim.x + threadIdx.x;
    if (t >= n4) return;

    const float4* x4 = (const float4*)x;
    float4 v = x4[t];

    // per-element op
    float y0, y1, y2, y3;
    {
        float f = v.x - truncf(v.x);
        y0 = (f > thr) ? rintf(v.x) : floorf(v.x);
    }
    {
        float f = v.y - truncf(v.y);
        y1 = (f > thr) ? rintf(v.y) : floorf(v.y);
    }
    {
        float f = v.z - truncf(v.z);
        y2 = (f > thr) ? rintf(v.z) : floorf(v.z);
    }
    {
        float f = v.w - truncf(v.w);
        y3 = (f > thr) ? rintf(v.w) : floorf(v.w);
    }

    // input elems i = 4t..4t+3 map to out positions n-1-i,
    // i.e. out[n-4-4t .. n-1-4t] = {y3, y2, y1, y0}
    float4 o;
    o.x = y3;
    o.y = y2;
    o.z = y1;
    o.w = y0;
    float4* out4 = (float4*)(out + (n - 4 - 4 * t));
    *out4 = o;
}

extern "C" void kernel_launch(void* const* d_in, const int* in_sizes, int n_in,
                              void* d_out, int out_size, void* d_ws, size_t ws_size,
                              hipStream_t stream) {
    const float* x = (const float*)d_in[0];
    const float* thr = (const float*)d_in[1];
    float* out = (float*)d_out;
    int n = in_sizes[0];       // 33554432, divisible by 4
    int n4 = n / 4;
    int block = 256;
    int grid = (n4 + block - 1) / block;
    threshold_rev_kernel<<<grid, block, 0, stream>>>(x, thr, out, n4, n);
}

// Round 3
// 218.065 us; speedup vs baseline: 1.0245x; 1.0245x over previous
//
#include <hip/hip_runtime.h>
#include <hip/hip_bf16.h>

// Element-wise threshold-round with reversed output order.
// y[i] = (x[i]-trunc(x[i]) > thr) ? rint(x[i]) : floor(x[i]);  out = y[::-1]
//
// Memory-bound: 128 MiB in + 128 MiB out. Both the 16B load AND the 16B
// store are lane-ascending contiguous: the output reversal is done by
// (a) swapping components within the vec4 and (b) a cross-lane shuffle
// lane l <-> lane 63-l, so each wave stores one ascending 1 KiB segment.
// Nontemporal hints: pure streaming, zero reuse. Native clang vector type
// (ext_vector_type) because __builtin_nontemporal_* rejects HIP_vector_type.

typedef float vfloat4 __attribute__((ext_vector_type(4)));

__global__ __launch_bounds__(256) void threshold_rev_kernel(
    const vfloat4* __restrict__ x4,
    const float* __restrict__ threshold,
    vfloat4* __restrict__ out4,
    int n4 /* number of float4 groups = N/4 */) {
    const float thr = threshold[0];
    const int t = blockIdx.x * blockDim.x + threadIdx.x;
    if (t >= n4) return;                 // n4 is a multiple of 64; wave-uniform
    const int lane = threadIdx.x & 63;
    const int wave_base = t - lane;      // first group handled by this wave

    vfloat4 v = __builtin_nontemporal_load(&x4[t]);

    // op per element, components reversed: r = {op(v3), op(v2), op(v1), op(v0)}
    vfloat4 r;
    {
        float f = v.w - truncf(v.w);
        r.x = (f > thr) ? rintf(v.w) : floorf(v.w);
    }
    {
        float f = v.z - truncf(v.z);
        r.y = (f > thr) ? rintf(v.z) : floorf(v.z);
    }
    {
        float f = v.y - truncf(v.y);
        r.z = (f > thr) ? rintf(v.y) : floorf(v.y);
    }
    {
        float f = v.x - truncf(v.x);
        r.w = (f > thr) ? rintf(v.x) : floorf(v.x);
    }

    // lane l takes the result computed by lane 63-l, so stores ascend with lane.
    const int src = 63 - lane;
    vfloat4 s;
    s.x = __shfl(r.x, src);
    s.y = __shfl(r.y, src);
    s.z = __shfl(r.z, src);
    s.w = __shfl(r.w, src);

    // input group of lane (63-l) is wave_base + 63 - l; its output group is
    // n4-1-(wave_base+63-l) = (n4-64-wave_base) + l  -> ascending in lane.
    const int og = (n4 - 64 - wave_base) + lane;
    __builtin_nontemporal_store(s, &out4[og]);
}

extern "C" void kernel_launch(void* const* d_in, const int* in_sizes, int n_in,
                              void* d_out, int out_size, void* d_ws, size_t ws_size,
                              hipStream_t stream) {
    const vfloat4* x4 = (const vfloat4*)d_in[0];
    const float* thr = (const float*)d_in[1];
    vfloat4* out4 = (vfloat4*)d_out;
    int n = in_sizes[0];       // 33554432, divisible by 1024
    int n4 = n / 4;
    int block = 256;
    int grid = (n4 + block - 1) / block;
    threshold_rev_kernel<<<grid, block, 0, stream>>>(x4, thr, out4, n4);
}